// Round 25
// baseline (673.386 us; speedup 1.0000x reference)
//
#include <hip/hip_runtime.h>

typedef short short8 __attribute__((ext_vector_type(8)));
typedef float f32x4 __attribute__((ext_vector_type(4)));
typedef unsigned short u16;

#define TOK_N 8192      // B*S
#define DMODEL 1024
#define NEXP 16
#define FEXP 512
#define NROUTED 14
#define KSEL 6
#define MAXTILES 400    // sum ceil(cnt_e/128) <= 49152/128 + 16 (divisible by 8)

__device__ __forceinline__ u16 f2bf(float f) {
  unsigned u = __float_as_uint(f);
  u += 0x7fff + ((u >> 16) & 1);   // round-to-nearest-even
  return (u16)(u >> 16);
}

typedef const __attribute__((address_space(1))) unsigned int* gas_p;
typedef __attribute__((address_space(3))) unsigned int* las_p;
// wave-uniform LDS base + lane*16; per-lane global src (16B each)
__device__ __forceinline__ void gload_lds16(const void* g, void* l) {
  __builtin_amdgcn_global_load_lds((gas_p)g, (las_p)l, 16, 0, 0);
}

// ---------------- cast f32 -> bf16 (token stream) ----------------
__global__ void cast_bf16_k(const float* __restrict__ in, u16* __restrict__ out, int n8) {
  int i = blockIdx.x * blockDim.x + threadIdx.x;
  if (i >= n8) return;
  const float4* p = (const float4*)(in + (size_t)i * 8);
  float4 a = p[0], b = p[1];
  short8 v;
  v[0] = (short)f2bf(a.x); v[1] = (short)f2bf(a.y); v[2] = (short)f2bf(a.z); v[3] = (short)f2bf(a.w);
  v[4] = (short)f2bf(b.x); v[5] = (short)f2bf(b.y); v[6] = (short)f2bf(b.z); v[7] = (short)f2bf(b.w);
  *(short8*)(out + (size_t)i * 8) = v;
}

// ------------- transpose + cast: in [e][R][C] f32 -> out [e][C][R] bf16 -------------
__global__ void transpose_cast_k(const float* __restrict__ in, u16* __restrict__ out, int R, int C) {
  __shared__ u16 tile[32][33];
  int e = blockIdx.z;
  int c0 = blockIdx.x * 32, r0 = blockIdx.y * 32;
  int x = threadIdx.x, y = threadIdx.y;   // block (32,8)
  const float* ip = in + ((size_t)e * R + r0) * C + c0;
  #pragma unroll
  for (int i = 0; i < 4; i++)
    tile[y + 8 * i][x] = f2bf(ip[(size_t)(y + 8 * i) * C + x]);
  __syncthreads();
  u16* op = out + ((size_t)e * C + c0) * R + r0;
  #pragma unroll
  for (int i = 0; i < 4; i++)
    op[(size_t)(y + 8 * i) * R + x] = tile[x][y + 8 * i];
}

// ---------------- routing pass A: logits, sigmoid, stable top-4 (NO global atomics) ----
__global__ void routing_k(const float* __restrict__ selin, const float* __restrict__ esel,
                          const float* __restrict__ bias, float* __restrict__ out_sel,
                          unsigned* __restrict__ sel_pack, float* __restrict__ aff6) {
  int tok = blockIdx.x;
  int t = threadIdx.x;
  int e = t & 15, chunk = t >> 4;          // 16 experts x 16 chunks of 64 elems
  const float4* r4 = (const float4*)(selin + (size_t)tok * DMODEL + chunk * 64);
  const float4* w4 = (const float4*)(esel + (size_t)e * DMODEL + chunk * 64);
  float p = 0.f;
  #pragma unroll
  for (int i = 0; i < 16; i++) {
    float4 a = r4[i], b = w4[i];
    p += a.x * b.x + a.y * b.y + a.z * b.z + a.w * b.w;
  }
  __shared__ float part[16][17];
  __shared__ float aff[16];
  __shared__ float lbias[NROUTED];
  if (t < NROUTED) lbias[t] = bias[t];
  part[chunk][e] = p;
  __syncthreads();
  if (t < 16) {
    float s = 0.f;
    #pragma unroll
    for (int c = 0; c < 16; c++) s += part[c][t];
    aff[t] = 1.f / (1.f + expf(-s));
  }
  __syncthreads();
  if (t == 0) {
    unsigned pack = 0;
    unsigned taken = 0;
    #pragma unroll
    for (int k = 0; k < 4; k++) {
      float best = -3.4e38f; int bi = 0;
      for (int q = 0; q < NROUTED; q++) {
        if (taken & (1u << q)) continue;
        float v = aff[q] + lbias[q];
        if (v > best) { best = v; bi = q; }   // strict > => lowest index wins ties (top_k stable)
      }
      taken |= 1u << bi;
      pack |= (unsigned)bi << (4 * k);
      out_sel[(size_t)tok * KSEL + k] = (float)bi;
      aff6[(size_t)tok * KSEL + k] = aff[bi];
    }
    pack |= 14u << 16; pack |= 15u << 20;
    out_sel[(size_t)tok * KSEL + 4] = 14.f;
    out_sel[(size_t)tok * KSEL + 5] = 15.f;
    aff6[(size_t)tok * KSEL + 4] = aff[14];
    aff6[(size_t)tok * KSEL + 5] = aff[15];
    sel_pack[tok] = pack;
  }
}

// ---------------- routing pass B: hierarchical scatter into per-expert lists ----------
// counts padded: expert e lives at counts[e*16] (64B stride -> no cache-line sharing)
__global__ void scatter_k(const unsigned* __restrict__ sel_pack, const float* __restrict__ aff6,
                          int* __restrict__ counts, int* __restrict__ tokk,
                          float* __restrict__ affl) {
  __shared__ int lcnt[16], lbase[16], lcur[16];
  int t = threadIdx.x;
  int tok = blockIdx.x * 256 + t;
  if (t < 16) lcnt[t] = 0;
  __syncthreads();
  unsigned pack = sel_pack[tok];
  int eid[KSEL];
  #pragma unroll
  for (int k = 0; k < KSEL; k++) {
    eid[k] = (pack >> (4 * k)) & 15;
    atomicAdd(&lcnt[eid[k]], 1);
  }
  __syncthreads();
  if (t < 16) {
    lbase[t] = atomicAdd(&counts[t * 16], lcnt[t]);
    lcur[t] = 0;
  }
  __syncthreads();
  #pragma unroll
  for (int k = 0; k < KSEL; k++) {
    int e = eid[k];
    int slot = lbase[e] + atomicAdd(&lcur[e], 1);
    tokk[e * TOK_N + slot] = tok * 8 + k;
    affl[e * TOK_N + slot] = aff6[(size_t)tok * KSEL + k];
  }
}

// ---------------- build compact tile list + per-expert prefix base, parallel ----------
// tiles[slot] = e | (mtile << 8); pbase[e] = exclusive prefix of raw counts (scores
// rows are packed per-expert in list order). All LDS-indexed (no scratch, rule #20).
__global__ void tilelist_k(const int* __restrict__ counts, int* __restrict__ tiles,
                           int* __restrict__ ntiles, int* __restrict__ pbase) {
  __shared__ int tc[16], pb[16];
  int t = threadIdx.x;   // 64 threads
  if (t < 16) tc[t] = (counts[t * 16] + 127) >> 7;
  __syncthreads();
  if (t == 0) {
    int s = 0;
    for (int e = 0; e < 16; e++) { pb[e] = s; s += tc[e]; }
    *ntiles = s;
    int s2 = 0;
    for (int e = 0; e < 16; e++) { pbase[e] = s2; s2 += counts[e * 16]; }
  }
  __syncthreads();
  if (t < 16) {
    int b = pb[t], n = tc[t];
    for (int i = 0; i < n; i++) tiles[b + i] = t | (i << 8);
  }
}

// ---------------- grouped GEMM: R9 simple core + R14 list-order + R23 XCD remap ------
// COMPOSITION of the three proven wins, no explicit pipeline:
//  - R9 core (best per-GEMM ever, 181us): 128x128xBK=64, 256 thr / 4 waves (2x2,
//    64x64 each, acc[4][4]), SINGLE-buffered 32KB LDS, plain 2-barrier K-loop
//    (compiler-scheduled waits). High co-residency (up to 5 blocks/CU) supplies TLP.
//  - R14: scores in per-expert list order (contiguous pass-3 A, no gather).
//  - R23: XCD-chunked slot remap -> B panels + gathered A L2-RESIDENT (FETCH 36MB =
//    unique-byte floor). R9 ran pre-remap with ~500-900cy exposed miss latency; now
//    the same exposed load is an L2 hit (~200cy) -- the unpipelined core gains most.
// XOR swizzle: linear LDS dest + pre-swizzled source chunk j^(row&7) + same on read.
// PASS 2: A = Xbf gathered by token; B = keysT; AK=1024; NY=4;
//         epilogue aff*silu -> bf16 scores, contiguous list-order rows.
// PASS 3: A = scores (contiguous); B = valuesT; AK=512; NY=8;
//         epilogue: f32 atomicAdd scatter into out[tok][1024].
template<int AK, int PASS, int NY>
__global__ __launch_bounds__(256, 5) void moe_gemm_k(
    const u16* __restrict__ Abase, const u16* __restrict__ Bbase,
    const int* __restrict__ counts, const int* __restrict__ tokk,
    const float* __restrict__ affl, const int* __restrict__ tiles,
    const int* __restrict__ ntiles, const int* __restrict__ pbase,
    u16* __restrict__ scores_out, float* __restrict__ out) {
  int p = blockIdx.x;
  int xcd = p & 7;
  int i = p >> 3;                       // [0, 50*NY)
  int slot = xcd * (MAXTILES / 8) + i / NY;
  int y = i % NY;
  if (slot >= *ntiles) return;
  int desc = tiles[slot];
  int e = desc & 15;
  int m0 = (desc >> 8) << 7;
  int cnt = counts[e * 16];
  int pbe = pbase[e];
  int n0 = y * 128;
  int t = threadIdx.x;
  int lane = t & 63, w = t >> 6;
  int wr = w >> 1, wc = w & 1;   // 2x2 waves, each 64x64

  __shared__ u16 Al[128][64];    // single-buffered; linear (global_load_lds dest)
  __shared__ u16 Bl[128][64];    // 32 KB total -> up to 5 blocks/CU

  const int* tl = tokk + e * TOK_N + m0;
  const float* al = affl + e * TOK_N + m0;
  const u16* Bp = Bbase + (size_t)e * 524288;

  f32x4 acc[4][4];
  #pragma unroll
  for (int m = 0; m < 4; m++)
    #pragma unroll
    for (int n = 0; n < 4; n++)
      acc[m][n] = (f32x4){0.f, 0.f, 0.f, 0.f};

  // staging geometry: per r (r<4), wave w stages rows [r*32+w*8, +8): 64 lanes x 16B.
  // lane -> row = base + (lane>>3), chunk j = lane&7; source chunk pre-swizzled j^(row&7).
  int jj = lane & 7, rl = lane >> 3;
  const u16* ag[4]; const u16* bg[4];
  #pragma unroll
  for (int r = 0; r < 4; r++) {
    int row = r * 32 + w * 8 + rl;
    int lr = (m0 + row < cnt) ? row : 0;   // clamp to a valid row (masked at epilogue)
    int ar;
    if (PASS == 2) {
      int tk = tl[lr];
      ar = tk >> 3;                        // gather X row by token
    } else {
      ar = pbe + m0 + lr;                  // contiguous list-order scores row
    }
    int cs = (jj ^ (row & 7)) * 8;         // swizzled source element offset
    ag[r] = Abase + (size_t)ar * AK + cs;
    bg[r] = Bp + (size_t)(n0 + row) * AK + cs;
  }

  for (int k0 = 0; k0 < AK; k0 += 64) {
    #pragma unroll
    for (int r = 0; r < 4; r++) {
      gload_lds16(ag[r] + k0, &Al[r * 32 + w * 8][0]);
      gload_lds16(bg[r] + k0, &Bl[r * 32 + w * 8][0]);
    }
    __syncthreads();   // drains vmcnt -> LDS tiles ready
    #pragma unroll
    for (int kk = 0; kk < 2; kk++) {
      int lc = kk * 4 + (lane >> 4);       // logical 16B chunk within row
      short8 af[4], bf[4];
      #pragma unroll
      for (int m = 0; m < 4; m++) {
        int row = wr * 64 + m * 16 + (lane & 15);
        af[m] = *(const short8*)&Al[row][(lc ^ (row & 7)) * 8];
      }
      #pragma unroll
      for (int n = 0; n < 4; n++) {
        int row = wc * 64 + n * 16 + (lane & 15);
        bf[n] = *(const short8*)&Bl[row][(lc ^ (row & 7)) * 8];
      }
      #pragma unroll
      for (int m = 0; m < 4; m++)
        #pragma unroll
        for (int n = 0; n < 4; n++)
          acc[m][n] = __builtin_amdgcn_mfma_f32_16x16x32_bf16(af[m], bf[n], acc[m][n], 0, 0, 0);
    }
    __syncthreads();
  }

  int cbase = n0 + wc * 64 + (lane & 15);
  #pragma unroll
  for (int m = 0; m < 4; m++) {
    int rbase = wr * 64 + m * 16 + ((lane >> 4) << 2);   // C/D: col=lane&15, row=(lane>>4)*4+q
    #pragma unroll
    for (int q = 0; q < 4; q++) {
      int row = rbase + q;
      if (m0 + row >= cnt) continue;
      if (PASS == 2) {
        float aff = al[row];
        size_t base = (size_t)(pbe + m0 + row) * FEXP;   // contiguous list-order row
        #pragma unroll
        for (int n = 0; n < 4; n++) {
          float v = acc[m][n][q];
          float s = aff * v / (1.f + expf(-v));   // aff * silu(v)
          scores_out[base + cbase + n * 16] = f2bf(s);
        }
      } else {
        int tk = tl[row];
        size_t base = (size_t)(tk >> 3) * DMODEL;
        #pragma unroll
        for (int n = 0; n < 4; n++)
          atomicAdd(&out[base + cbase + n * 16], acc[m][n][q]);
      }
    }
  }
}

extern "C" void kernel_launch(void* const* d_in, const int* in_sizes, int n_in,
                              void* d_out, int out_size, void* d_ws, size_t ws_size,
                              hipStream_t stream) {
  (void)in_sizes; (void)n_in; (void)out_size; (void)ws_size;
  const float* token_stream    = (const float*)d_in[0];
  const float* selection_input = (const float*)d_in[1];
  const float* keys_w          = (const float*)d_in[2];
  const float* values_w        = (const float*)d_in[3];
  const float* expert_sel      = (const float*)d_in[4];
  const float* bias_ffn        = (const float*)d_in[5];

  float* out     = (float*)d_out;                       // [8192][1024] f32
  float* out_sel = out + (size_t)TOK_N * DMODEL;        // [8192][6] as float

  char* ws = (char*)d_ws;
  u16*      Xbf      = (u16*)(ws + 0);                  // 16 MB
  u16*      keysT    = (u16*)(ws + 16777216);           // 16 MB  [e][512][1024]
  u16*      valuesT  = (u16*)(ws + 33554432);           // 16 MB  [e][1024][512]
  u16*      scoresbf = (u16*)(ws + 50331648);           // 48 MB  [49152 list-order][512]
  int*      counts   = (int*)(ws + 100663296);          // 1 KB (padded, e -> counts[e*16])
  int*      tokk     = (int*)(ws + 100664320);          // 512 KB
  float*    affl     = (float*)(ws + 101188608);        // 512 KB
  unsigned* sel_pack = (unsigned*)(ws + 101712896);     // 32 KB
  float*    aff6     = (float*)(ws + 101745664);        // 192 KB
  int*      tiles    = (int*)(ws + 101942272);          // 4 KB
  int*      ntiles   = (int*)(ws + 101946368);          // 4 B
  int*      pbase    = (int*)(ws + 101946432);          // 64 B

  hipMemsetAsync(out, 0, (size_t)TOK_N * DMODEL * sizeof(float), stream);
  hipMemsetAsync(counts, 0, 1024, stream);

  cast_bf16_k<<<4096, 256, 0, stream>>>(token_stream, Xbf, TOK_N * DMODEL / 8);
  transpose_cast_k<<<dim3(16, 32, 16), dim3(32, 8), 0, stream>>>(keys_w, keysT, 1024, 512);
  transpose_cast_k<<<dim3(32, 16, 16), dim3(32, 8), 0, stream>>>(values_w, valuesT, 512, 1024);

  routing_k<<<TOK_N, 256, 0, stream>>>(selection_input, expert_sel, bias_ffn,
                                       out_sel, sel_pack, aff6);
  scatter_k<<<TOK_N / 256, 256, 0, stream>>>(sel_pack, aff6, counts, tokk, affl);
  tilelist_k<<<1, 64, 0, stream>>>(counts, tiles, ntiles, pbase);

  // scores = aff * silu(X @ K[e]):  M<=49152, N=512, K=1024
  moe_gemm_k<1024, 2, 4><<<MAXTILES * 4, 256, 0, stream>>>(Xbf, keysT, counts, tokk, affl,
                                                           tiles, ntiles, pbase,
                                                           scoresbf, nullptr);
  // out += scores @ V[e]:          M<=49152, N=1024, K=512
  moe_gemm_k<512, 3, 8><<<MAXTILES * 8, 256, 0, stream>>>(scoresbf, valuesT, counts, tokk, affl,
                                                          tiles, ntiles, pbase,
                                                          nullptr, out);
}

// Round 26
// 405.032 us; speedup vs baseline: 1.6625x; 1.6625x over previous
//
#include <hip/hip_runtime.h>

typedef short short8 __attribute__((ext_vector_type(8)));
typedef float f32x4 __attribute__((ext_vector_type(4)));
typedef unsigned short u16;

#define TOK_N 8192      // B*S
#define DMODEL 1024
#define NEXP 16
#define FEXP 512
#define NROUTED 14
#define KSEL 6
#define MAXTILES 400    // sum ceil(cnt_e/128) <= 49152/128 + 16 (divisible by 8)

__device__ __forceinline__ u16 f2bf(float f) {
  unsigned u = __float_as_uint(f);
  u += 0x7fff + ((u >> 16) & 1);   // round-to-nearest-even
  return (u16)(u >> 16);
}

typedef const __attribute__((address_space(1))) unsigned int* gas_p;
typedef __attribute__((address_space(3))) unsigned int* las_p;
// wave-uniform LDS base + lane*16; per-lane global src (16B each)
__device__ __forceinline__ void gload_lds16(const void* g, void* l) {
  __builtin_amdgcn_global_load_lds((gas_p)g, (las_p)l, 16, 0, 0);
}

// ---------------- cast f32 -> bf16 (token stream) ----------------
__global__ void cast_bf16_k(const float* __restrict__ in, u16* __restrict__ out, int n8) {
  int i = blockIdx.x * blockDim.x + threadIdx.x;
  if (i >= n8) return;
  const float4* p = (const float4*)(in + (size_t)i * 8);
  float4 a = p[0], b = p[1];
  short8 v;
  v[0] = (short)f2bf(a.x); v[1] = (short)f2bf(a.y); v[2] = (short)f2bf(a.z); v[3] = (short)f2bf(a.w);
  v[4] = (short)f2bf(b.x); v[5] = (short)f2bf(b.y); v[6] = (short)f2bf(b.z); v[7] = (short)f2bf(b.w);
  *(short8*)(out + (size_t)i * 8) = v;
}

// ------------- transpose + cast: in [e][R][C] f32 -> out [e][C][R] bf16 -------------
__global__ void transpose_cast_k(const float* __restrict__ in, u16* __restrict__ out, int R, int C) {
  __shared__ u16 tile[32][33];
  int e = blockIdx.z;
  int c0 = blockIdx.x * 32, r0 = blockIdx.y * 32;
  int x = threadIdx.x, y = threadIdx.y;   // block (32,8)
  const float* ip = in + ((size_t)e * R + r0) * C + c0;
  #pragma unroll
  for (int i = 0; i < 4; i++)
    tile[y + 8 * i][x] = f2bf(ip[(size_t)(y + 8 * i) * C + x]);
  __syncthreads();
  u16* op = out + ((size_t)e * C + c0) * R + r0;
  #pragma unroll
  for (int i = 0; i < 4; i++)
    op[(size_t)(y + 8 * i) * R + x] = tile[x][y + 8 * i];
}

// ---------------- routing pass A: logits, sigmoid, stable top-4 (NO global atomics) ----
__global__ void routing_k(const float* __restrict__ selin, const float* __restrict__ esel,
                          const float* __restrict__ bias, float* __restrict__ out_sel,
                          unsigned* __restrict__ sel_pack, float* __restrict__ aff6) {
  int tok = blockIdx.x;
  int t = threadIdx.x;
  int e = t & 15, chunk = t >> 4;          // 16 experts x 16 chunks of 64 elems
  const float4* r4 = (const float4*)(selin + (size_t)tok * DMODEL + chunk * 64);
  const float4* w4 = (const float4*)(esel + (size_t)e * DMODEL + chunk * 64);
  float p = 0.f;
  #pragma unroll
  for (int i = 0; i < 16; i++) {
    float4 a = r4[i], b = w4[i];
    p += a.x * b.x + a.y * b.y + a.z * b.z + a.w * b.w;
  }
  __shared__ float part[16][17];
  __shared__ float aff[16];
  __shared__ float lbias[NROUTED];
  if (t < NROUTED) lbias[t] = bias[t];
  part[chunk][e] = p;
  __syncthreads();
  if (t < 16) {
    float s = 0.f;
    #pragma unroll
    for (int c = 0; c < 16; c++) s += part[c][t];
    aff[t] = 1.f / (1.f + expf(-s));
  }
  __syncthreads();
  if (t == 0) {
    unsigned pack = 0;
    unsigned taken = 0;
    #pragma unroll
    for (int k = 0; k < 4; k++) {
      float best = -3.4e38f; int bi = 0;
      for (int q = 0; q < NROUTED; q++) {
        if (taken & (1u << q)) continue;
        float v = aff[q] + lbias[q];
        if (v > best) { best = v; bi = q; }   // strict > => lowest index wins ties (top_k stable)
      }
      taken |= 1u << bi;
      pack |= (unsigned)bi << (4 * k);
      out_sel[(size_t)tok * KSEL + k] = (float)bi;
      aff6[(size_t)tok * KSEL + k] = aff[bi];
    }
    pack |= 14u << 16; pack |= 15u << 20;
    out_sel[(size_t)tok * KSEL + 4] = 14.f;
    out_sel[(size_t)tok * KSEL + 5] = 15.f;
    aff6[(size_t)tok * KSEL + 4] = aff[14];
    aff6[(size_t)tok * KSEL + 5] = aff[15];
    sel_pack[tok] = pack;
  }
}

// ---------------- routing pass B: hierarchical scatter into per-expert lists ----------
// counts padded: expert e lives at counts[e*16] (64B stride -> no cache-line sharing)
__global__ void scatter_k(const unsigned* __restrict__ sel_pack, const float* __restrict__ aff6,
                          int* __restrict__ counts, int* __restrict__ tokk,
                          float* __restrict__ affl) {
  __shared__ int lcnt[16], lbase[16], lcur[16];
  int t = threadIdx.x;
  int tok = blockIdx.x * 256 + t;
  if (t < 16) lcnt[t] = 0;
  __syncthreads();
  unsigned pack = sel_pack[tok];
  int eid[KSEL];
  #pragma unroll
  for (int k = 0; k < KSEL; k++) {
    eid[k] = (pack >> (4 * k)) & 15;
    atomicAdd(&lcnt[eid[k]], 1);
  }
  __syncthreads();
  if (t < 16) {
    lbase[t] = atomicAdd(&counts[t * 16], lcnt[t]);
    lcur[t] = 0;
  }
  __syncthreads();
  #pragma unroll
  for (int k = 0; k < KSEL; k++) {
    int e = eid[k];
    int slot = lbase[e] + atomicAdd(&lcur[e], 1);
    tokk[e * TOK_N + slot] = tok * 8 + k;
    affl[e * TOK_N + slot] = aff6[(size_t)tok * KSEL + k];
  }
}

// ---------------- build compact tile list + per-expert prefix base, parallel ----------
// tiles[slot] = e | (mtile << 8); pbase[e] = exclusive prefix of raw counts (scores
// rows are packed per-expert in list order). All LDS-indexed (no scratch, rule #20).
__global__ void tilelist_k(const int* __restrict__ counts, int* __restrict__ tiles,
                           int* __restrict__ ntiles, int* __restrict__ pbase) {
  __shared__ int tc[16], pb[16];
  int t = threadIdx.x;   // 64 threads
  if (t < 16) tc[t] = (counts[t * 16] + 127) >> 7;
  __syncthreads();
  if (t == 0) {
    int s = 0;
    for (int e = 0; e < 16; e++) { pb[e] = s; s += tc[e]; }
    *ntiles = s;
    int s2 = 0;
    for (int e = 0; e < 16; e++) { pbase[e] = s2; s2 += counts[e * 16]; }
  }
  __syncthreads();
  if (t < 16) {
    int b = pb[t], n = tc[t];
    for (int i = 0; i < n; i++) tiles[b + i] = t | (i << 8);
  }
}

// ---------------- grouped GEMM: R22 core + per-XCD contiguous slot chunks (=R23) -----
// BEST MEASURED (407us). 128x128xBK=64, 8 waves (2Mx4N, 64x32/wave), LDS 2x32KB dbuf
// (2 blocks/CU -> per-XCD live working set ~4MB = L2-sized; R25 proved 5 blocks/CU
// thrashes: FETCH 36->435MB), XOR swizzle (0 conflicts), counted-vmcnt schedule
// (VWAIT4; never vmcnt(0) in main loop). XCD-chunked remap: x=p&7, XCD x owns slots
// [x*50, x*50+50), y-innermost -> B panels + gathered A L2-resident (FETCH at
// unique-byte floor, 36MB).
// PASS 2: A = Xbf gathered by token; B = keysT; AK=1024; NY=4;
//         epilogue aff*silu -> bf16 scores, contiguous list-order rows (R14).
// PASS 3: A = scores (contiguous, no gather); B = valuesT; AK=512; NY=8;
//         epilogue: f32 atomicAdd scatter into out[tok][1024].
template<int AK, int PASS, int NY>
__global__ __launch_bounds__(512, 2) void moe_gemm_k(
    const u16* __restrict__ Abase, const u16* __restrict__ Bbase,
    const int* __restrict__ counts, const int* __restrict__ tokk,
    const float* __restrict__ affl, const int* __restrict__ tiles,
    const int* __restrict__ ntiles, const int* __restrict__ pbase,
    u16* __restrict__ scores_out, float* __restrict__ out) {
  int p = blockIdx.x;
  int xcd = p & 7;
  int i = p >> 3;                       // [0, 50*NY)
  int slot = xcd * (MAXTILES / 8) + i / NY;
  int y = i % NY;
  if (slot >= *ntiles) return;
  int desc = tiles[slot];
  int e = desc & 15;
  int m0 = (desc >> 8) << 7;
  int cnt = counts[e * 16];
  int pbe = pbase[e];
  int n0 = y * 128;
  int t = threadIdx.x;
  int lane = t & 63, w = t >> 6;   // 8 waves
  int wr = w >> 2, wc = w & 3;     // 2x4 waves, each 64x32

  __shared__ u16 Al[2][128][64];   // double-buffered; linear (global_load_lds dest)
  __shared__ u16 Bl[2][128][64];

  const int* tl = tokk + e * TOK_N + m0;
  const float* al = affl + e * TOK_N + m0;
  const u16* Bp = Bbase + (size_t)e * 524288;

  f32x4 acc[4][2];
  #pragma unroll
  for (int m = 0; m < 4; m++)
    #pragma unroll
    for (int n = 0; n < 2; n++)
      acc[m][n] = (f32x4){0.f, 0.f, 0.f, 0.f};

  // staging geometry: wave w stages A+B rows [w*16, w*16+16), 8 rows per gload
  // (lane -> row = base + (lane>>3), chunk j = lane&7; row&7 == lane>>3).
  // Source chunk pre-swizzled j ^ (row&7) (rule #21: linear dest, swizzled src).
  int jj = lane & 7, rl = lane >> 3;
  const u16* ag[2]; const u16* bg[2];
  #pragma unroll
  for (int r = 0; r < 2; r++) {
    int row = w * 16 + r * 8 + rl;
    int lr = (m0 + row < cnt) ? row : 0;   // clamp to a valid row (masked at epilogue)
    int ar;
    if (PASS == 2) {
      int tk = tl[lr];
      ar = tk >> 3;                        // gather X row by token
    } else {
      ar = pbe + m0 + lr;                  // contiguous list-order scores row
    }
    int cs = (jj ^ (row & 7)) * 8;         // swizzled source element offset
    ag[r] = Abase + (size_t)ar * AK + cs;
    bg[r] = Bp + (size_t)(n0 + row) * AK + cs;
  }

#define STAGE(B, K0)                                             \
  _Pragma("unroll")                                              \
  for (int r = 0; r < 2; r++) {                                  \
    gload_lds16(ag[r] + (K0), &Al[B][w * 16 + r * 8][0]);        \
    gload_lds16(bg[r] + (K0), &Bl[B][w * 16 + r * 8][0]);        \
  }

#define COMPUTE(B)                                                         \
  _Pragma("unroll")                                                        \
  for (int kk = 0; kk < 2; kk++) {                                         \
    int lc = kk * 4 + (lane >> 4);                                         \
    short8 af[4], bf[2];                                                   \
    _Pragma("unroll")                                                      \
    for (int m = 0; m < 4; m++) {                                          \
      int row = wr * 64 + m * 16 + (lane & 15);                            \
      af[m] = *(const short8*)&Al[B][row][(lc ^ (row & 7)) * 8];           \
    }                                                                      \
    _Pragma("unroll")                                                      \
    for (int n = 0; n < 2; n++) {                                          \
      int row = wc * 32 + n * 16 + (lane & 15);                            \
      bf[n] = *(const short8*)&Bl[B][row][(lc ^ (row & 7)) * 8];           \
    }                                                                      \
    _Pragma("unroll")                                                      \
    for (int m = 0; m < 4; m++)                                            \
      _Pragma("unroll")                                                    \
      for (int n = 0; n < 2; n++)                                          \
        acc[m][n] = __builtin_amdgcn_mfma_f32_16x16x32_bf16(af[m], bf[n],  \
                                                            acc[m][n], 0, 0, 0); \
  }

#define VWAIT4 asm volatile("s_waitcnt vmcnt(4)" ::: "memory")
#define VWAIT0 asm volatile("s_waitcnt vmcnt(0)" ::: "memory")
#define BARR  __builtin_amdgcn_s_barrier()
#define PIN   __builtin_amdgcn_sched_barrier(0)

  constexpr int NIT = AK / 64;   // 16 (pass2) / 8 (pass3) -- even, >= 4
  STAGE(0, 0)                    // 4 loads in flight (buf0)
  #pragma unroll 1
  for (int it = 0; it < NIT - 2; it += 2) {
    STAGE(1, (it + 1) * 64)      // +4 -> 8 in flight
    VWAIT4; BARR; PIN;           // buf0 done everywhere; buf1 loads still flying
    COMPUTE(0)
    BARR; PIN;                   // all waves done reading buf0 -> safe to overwrite
    STAGE(0, (it + 2) * 64)
    VWAIT4; BARR; PIN;           // buf1 done; buf0-next still flying
    COMPUTE(1)
    BARR; PIN;
  }
  // peeled tail: it = NIT-2
  STAGE(1, (NIT - 1) * 64)
  VWAIT4; BARR; PIN;
  COMPUTE(0)
  BARR; PIN;
  VWAIT0; BARR; PIN;             // drain buf1's loads
  COMPUTE(1)

#undef STAGE
#undef COMPUTE
#undef VWAIT4
#undef VWAIT0
#undef BARR
#undef PIN

  int cbase = n0 + wc * 32 + (lane & 15);
  #pragma unroll
  for (int m = 0; m < 4; m++) {
    int rbase = wr * 64 + m * 16 + ((lane >> 4) << 2);   // C/D: col=lane&15, row=(lane>>4)*4+q
    #pragma unroll
    for (int q = 0; q < 4; q++) {
      int row = rbase + q;
      if (m0 + row >= cnt) continue;
      if (PASS == 2) {
        float aff = al[row];
        size_t base = (size_t)(pbe + m0 + row) * FEXP;   // contiguous list-order row
        #pragma unroll
        for (int n = 0; n < 2; n++) {
          float v = acc[m][n][q];
          float s = aff * v / (1.f + expf(-v));   // aff * silu(v)
          scores_out[base + cbase + n * 16] = f2bf(s);
        }
      } else {
        int tk = tl[row];
        size_t base = (size_t)(tk >> 3) * DMODEL;
        #pragma unroll
        for (int n = 0; n < 2; n++)
          atomicAdd(&out[base + cbase + n * 16], acc[m][n][q]);
      }
    }
  }
}

extern "C" void kernel_launch(void* const* d_in, const int* in_sizes, int n_in,
                              void* d_out, int out_size, void* d_ws, size_t ws_size,
                              hipStream_t stream) {
  (void)in_sizes; (void)n_in; (void)out_size; (void)ws_size;
  const float* token_stream    = (const float*)d_in[0];
  const float* selection_input = (const float*)d_in[1];
  const float* keys_w          = (const float*)d_in[2];
  const float* values_w        = (const float*)d_in[3];
  const float* expert_sel      = (const float*)d_in[4];
  const float* bias_ffn        = (const float*)d_in[5];

  float* out     = (float*)d_out;                       // [8192][1024] f32
  float* out_sel = out + (size_t)TOK_N * DMODEL;        // [8192][6] as float

  char* ws = (char*)d_ws;
  u16*      Xbf      = (u16*)(ws + 0);                  // 16 MB
  u16*      keysT    = (u16*)(ws + 16777216);           // 16 MB  [e][512][1024]
  u16*      valuesT  = (u16*)(ws + 33554432);           // 16 MB  [e][1024][512]
  u16*      scoresbf = (u16*)(ws + 50331648);           // 48 MB  [49152 list-order][512]
  int*      counts   = (int*)(ws + 100663296);          // 1 KB (padded, e -> counts[e*16])
  int*      tokk     = (int*)(ws + 100664320);          // 512 KB
  float*    affl     = (float*)(ws + 101188608);        // 512 KB
  unsigned* sel_pack = (unsigned*)(ws + 101712896);     // 32 KB
  float*    aff6     = (float*)(ws + 101745664);        // 192 KB
  int*      tiles    = (int*)(ws + 101942272);          // 4 KB
  int*      ntiles   = (int*)(ws + 101946368);          // 4 B
  int*      pbase    = (int*)(ws + 101946432);          // 64 B

  hipMemsetAsync(out, 0, (size_t)TOK_N * DMODEL * sizeof(float), stream);
  hipMemsetAsync(counts, 0, 1024, stream);

  cast_bf16_k<<<4096, 256, 0, stream>>>(token_stream, Xbf, TOK_N * DMODEL / 8);
  transpose_cast_k<<<dim3(16, 32, 16), dim3(32, 8), 0, stream>>>(keys_w, keysT, 1024, 512);
  transpose_cast_k<<<dim3(32, 16, 16), dim3(32, 8), 0, stream>>>(values_w, valuesT, 512, 1024);

  routing_k<<<TOK_N, 256, 0, stream>>>(selection_input, expert_sel, bias_ffn,
                                       out_sel, sel_pack, aff6);
  scatter_k<<<TOK_N / 256, 256, 0, stream>>>(sel_pack, aff6, counts, tokk, affl);
  tilelist_k<<<1, 64, 0, stream>>>(counts, tiles, ntiles, pbase);

  // scores = aff * silu(X @ K[e]):  M<=49152, N=512, K=1024
  moe_gemm_k<1024, 2, 4><<<MAXTILES * 4, 512, 0, stream>>>(Xbf, keysT, counts, tokk, affl,
                                                           tiles, ntiles, pbase,
                                                           scoresbf, nullptr);
  // out += scores @ V[e]:          M<=49152, N=1024, K=512
  moe_gemm_k<512, 3, 8><<<MAXTILES * 8, 512, 0, stream>>>(scoresbf, valuesT, counts, tokk, affl,
                                                          tiles, ntiles, pbase,
                                                          nullptr, out);
}

// Round 27
// 378.601 us; speedup vs baseline: 1.7786x; 1.0698x over previous
//
#include <hip/hip_runtime.h>

typedef short short8 __attribute__((ext_vector_type(8)));
typedef float f32x4 __attribute__((ext_vector_type(4)));
typedef unsigned short u16;

#define TOK_N 8192      // B*S
#define DMODEL 1024
#define NEXP 16
#define FEXP 512
#define NROUTED 14
#define KSEL 6
#define MAXTILES 400    // sum ceil(cnt_e/128) <= 49152/128 + 16 (divisible by 8)

__device__ __forceinline__ u16 f2bf(float f) {
  unsigned u = __float_as_uint(f);
  u += 0x7fff + ((u >> 16) & 1);   // round-to-nearest-even
  return (u16)(u >> 16);
}

typedef const __attribute__((address_space(1))) unsigned int* gas_p;
typedef __attribute__((address_space(3))) unsigned int* las_p;
// wave-uniform LDS base + lane*16; per-lane global src (16B each)
__device__ __forceinline__ void gload_lds16(const void* g, void* l) {
  __builtin_amdgcn_global_load_lds((gas_p)g, (las_p)l, 16, 0, 0);
}

// ---------------- fused prologue: routing + cast + both transposes (concurrent) ------
// blocks [0,8192): routing (token b); [8192,12288): cast X f32->bf16;
// [12288,20480): keys transpose [e][1024][512]->[e][512][1024];
// [20480,28672): values transpose [e][512][1024]->[e][1024][512].
// Each block takes exactly one branch (blockIdx-uniform) -> per-branch barriers legal.
__global__ __launch_bounds__(256) void prep_k(
    const float* __restrict__ token_stream, const float* __restrict__ selin,
    const float* __restrict__ keys_w, const float* __restrict__ values_w,
    const float* __restrict__ esel, const float* __restrict__ bias,
    u16* __restrict__ Xbf, u16* __restrict__ keysT, u16* __restrict__ valuesT,
    float* __restrict__ out_sel, unsigned* __restrict__ sel_pack,
    float* __restrict__ aff6) {
  __shared__ float part[16][17];
  __shared__ float aff[16];
  __shared__ float lbias[NROUTED];
  __shared__ u16 tile[32][33];
  int b = blockIdx.x;
  int t = threadIdx.x;

  if (b < 8192) {
    // ---- routing: logits, sigmoid, stable top-4 ----
    int tok = b;
    int e = t & 15, chunk = t >> 4;          // 16 experts x 16 chunks of 64 elems
    const float4* r4 = (const float4*)(selin + (size_t)tok * DMODEL + chunk * 64);
    const float4* w4 = (const float4*)(esel + (size_t)e * DMODEL + chunk * 64);
    float p = 0.f;
    #pragma unroll
    for (int i = 0; i < 16; i++) {
      float4 a = r4[i], c = w4[i];
      p += a.x * c.x + a.y * c.y + a.z * c.z + a.w * c.w;
    }
    if (t < NROUTED) lbias[t] = bias[t];
    part[chunk][e] = p;
    __syncthreads();
    if (t < 16) {
      float s = 0.f;
      #pragma unroll
      for (int c = 0; c < 16; c++) s += part[c][t];
      aff[t] = 1.f / (1.f + expf(-s));
    }
    __syncthreads();
    if (t == 0) {
      unsigned pack = 0;
      unsigned taken = 0;
      #pragma unroll
      for (int k = 0; k < 4; k++) {
        float best = -3.4e38f; int bi = 0;
        for (int q = 0; q < NROUTED; q++) {
          if (taken & (1u << q)) continue;
          float v = aff[q] + lbias[q];
          if (v > best) { best = v; bi = q; }   // strict > => lowest index wins ties
        }
        taken |= 1u << bi;
        pack |= (unsigned)bi << (4 * k);
        out_sel[(size_t)tok * KSEL + k] = (float)bi;
        aff6[(size_t)tok * KSEL + k] = aff[bi];
      }
      pack |= 14u << 16; pack |= 15u << 20;
      out_sel[(size_t)tok * KSEL + 4] = 14.f;
      out_sel[(size_t)tok * KSEL + 5] = 15.f;
      aff6[(size_t)tok * KSEL + 4] = aff[14];
      aff6[(size_t)tok * KSEL + 5] = aff[15];
      sel_pack[tok] = pack;
    }
  } else if (b < 12288) {
    // ---- cast X f32 -> bf16: 4096 blocks x 256 thr x 8 elems = 8192*1024 ----
    int i = (b - 8192) * 256 + t;
    const float4* p = (const float4*)(token_stream + (size_t)i * 8);
    float4 a = p[0], c = p[1];
    short8 v;
    v[0] = (short)f2bf(a.x); v[1] = (short)f2bf(a.y); v[2] = (short)f2bf(a.z); v[3] = (short)f2bf(a.w);
    v[4] = (short)f2bf(c.x); v[5] = (short)f2bf(c.y); v[6] = (short)f2bf(c.z); v[7] = (short)f2bf(c.w);
    *(short8*)(Xbf + (size_t)i * 8) = v;
  } else {
    // ---- transpose + cast: in [e][R][C] f32 -> out [e][C][R] bf16 ----
    const float* in; u16* outp; int R, C, c0, r0, e;
    if (b < 20480) {           // keys: R=1024, C=512; grid (16,32,16)
      int id = b - 12288;
      in = keys_w; outp = keysT; R = 1024; C = 512;
      c0 = (id & 15) * 32; r0 = ((id >> 4) & 31) * 32; e = id >> 9;
    } else {                   // values: R=512, C=1024; grid (32,16,16)
      int id = b - 20480;
      in = values_w; outp = valuesT; R = 512; C = 1024;
      c0 = (id & 31) * 32; r0 = ((id >> 5) & 15) * 32; e = id >> 9;
    }
    int x = t & 31, y = t >> 5;   // (32,8)
    const float* ip = in + ((size_t)e * R + r0) * C + c0;
    #pragma unroll
    for (int i = 0; i < 4; i++)
      tile[y + 8 * i][x] = f2bf(ip[(size_t)(y + 8 * i) * C + x]);
    __syncthreads();
    u16* op = outp + ((size_t)e * C + c0) * R + r0;
    #pragma unroll
    for (int i = 0; i < 4; i++)
      op[(size_t)(y + 8 * i) * R + x] = tile[x][y + 8 * i];
  }
}

// ---------------- routing pass B: hierarchical scatter into per-expert lists ----------
// counts padded: expert e lives at counts[e*16] (64B stride -> no cache-line sharing)
__global__ void scatter_k(const unsigned* __restrict__ sel_pack, const float* __restrict__ aff6,
                          int* __restrict__ counts, int* __restrict__ tokk,
                          float* __restrict__ affl) {
  __shared__ int lcnt[16], lbase[16], lcur[16];
  int t = threadIdx.x;
  int tok = blockIdx.x * 256 + t;
  if (t < 16) lcnt[t] = 0;
  __syncthreads();
  unsigned pack = sel_pack[tok];
  int eid[KSEL];
  #pragma unroll
  for (int k = 0; k < KSEL; k++) {
    eid[k] = (pack >> (4 * k)) & 15;
    atomicAdd(&lcnt[eid[k]], 1);
  }
  __syncthreads();
  if (t < 16) {
    lbase[t] = atomicAdd(&counts[t * 16], lcnt[t]);
    lcur[t] = 0;
  }
  __syncthreads();
  #pragma unroll
  for (int k = 0; k < KSEL; k++) {
    int e = eid[k];
    int slot = lbase[e] + atomicAdd(&lcur[e], 1);
    tokk[e * TOK_N + slot] = tok * 8 + k;
    affl[e * TOK_N + slot] = aff6[(size_t)tok * KSEL + k];
  }
}

// ---------------- build compact tile list + per-expert prefix base, parallel ----------
// tiles[slot] = e | (mtile << 8); pbase[e] = exclusive prefix of raw counts (scores
// rows are packed per-expert in list order). All LDS-indexed (no scratch, rule #20).
__global__ void tilelist_k(const int* __restrict__ counts, int* __restrict__ tiles,
                           int* __restrict__ ntiles, int* __restrict__ pbase) {
  __shared__ int tc[16], pb[16];
  int t = threadIdx.x;   // 64 threads
  if (t < 16) tc[t] = (counts[t * 16] + 127) >> 7;
  __syncthreads();
  if (t == 0) {
    int s = 0;
    for (int e = 0; e < 16; e++) { pb[e] = s; s += tc[e]; }
    *ntiles = s;
    int s2 = 0;
    for (int e = 0; e < 16; e++) { pbase[e] = s2; s2 += counts[e * 16]; }
  }
  __syncthreads();
  if (t < 16) {
    int b = pb[t], n = tc[t];
    for (int i = 0; i < n; i++) tiles[b + i] = t | (i << 8);
  }
}

// ---------------- grouped GEMM: R22 core + per-XCD contiguous slot chunks (=R23) -----
// BEST MEASURED (405us). 128x128xBK=64, 8 waves (2Mx4N, 64x32/wave), LDS 2x32KB dbuf
// (2 blocks/CU -> per-XCD live working set ~4MB = L2-sized; R25 proved 5 blocks/CU
// thrashes: FETCH 36->435MB), XOR swizzle (0 conflicts), counted-vmcnt schedule
// (VWAIT4; never vmcnt(0) in main loop). XCD-chunked remap: x=p&7, XCD x owns slots
// [x*50, x*50+50), y-innermost -> B panels + gathered A L2-resident (FETCH at
// unique-byte floor, 36MB).
// PASS 2: A = Xbf gathered by token; B = keysT; AK=1024; NY=4;
//         epilogue aff*silu -> bf16 scores, contiguous list-order rows (R14).
// PASS 3: A = scores (contiguous, no gather); B = valuesT; AK=512; NY=8;
//         epilogue: f32 atomicAdd scatter into out[tok][1024].
template<int AK, int PASS, int NY>
__global__ __launch_bounds__(512, 2) void moe_gemm_k(
    const u16* __restrict__ Abase, const u16* __restrict__ Bbase,
    const int* __restrict__ counts, const int* __restrict__ tokk,
    const float* __restrict__ affl, const int* __restrict__ tiles,
    const int* __restrict__ ntiles, const int* __restrict__ pbase,
    u16* __restrict__ scores_out, float* __restrict__ out) {
  int p = blockIdx.x;
  int xcd = p & 7;
  int i = p >> 3;                       // [0, 50*NY)
  int slot = xcd * (MAXTILES / 8) + i / NY;
  int y = i % NY;
  if (slot >= *ntiles) return;
  int desc = tiles[slot];
  int e = desc & 15;
  int m0 = (desc >> 8) << 7;
  int cnt = counts[e * 16];
  int pbe = pbase[e];
  int n0 = y * 128;
  int t = threadIdx.x;
  int lane = t & 63, w = t >> 6;   // 8 waves
  int wr = w >> 2, wc = w & 3;     // 2x4 waves, each 64x32

  __shared__ u16 Al[2][128][64];   // double-buffered; linear (global_load_lds dest)
  __shared__ u16 Bl[2][128][64];

  const int* tl = tokk + e * TOK_N + m0;
  const float* al = affl + e * TOK_N + m0;
  const u16* Bp = Bbase + (size_t)e * 524288;

  f32x4 acc[4][2];
  #pragma unroll
  for (int m = 0; m < 4; m++)
    #pragma unroll
    for (int n = 0; n < 2; n++)
      acc[m][n] = (f32x4){0.f, 0.f, 0.f, 0.f};

  // staging geometry: wave w stages A+B rows [w*16, w*16+16), 8 rows per gload
  // (lane -> row = base + (lane>>3), chunk j = lane&7; row&7 == lane>>3).
  // Source chunk pre-swizzled j ^ (row&7) (rule #21: linear dest, swizzled src).
  int jj = lane & 7, rl = lane >> 3;
  const u16* ag[2]; const u16* bg[2];
  #pragma unroll
  for (int r = 0; r < 2; r++) {
    int row = w * 16 + r * 8 + rl;
    int lr = (m0 + row < cnt) ? row : 0;   // clamp to a valid row (masked at epilogue)
    int ar;
    if (PASS == 2) {
      int tk = tl[lr];
      ar = tk >> 3;                        // gather X row by token
    } else {
      ar = pbe + m0 + lr;                  // contiguous list-order scores row
    }
    int cs = (jj ^ (row & 7)) * 8;         // swizzled source element offset
    ag[r] = Abase + (size_t)ar * AK + cs;
    bg[r] = Bp + (size_t)(n0 + row) * AK + cs;
  }

#define STAGE(B, K0)                                             \
  _Pragma("unroll")                                              \
  for (int r = 0; r < 2; r++) {                                  \
    gload_lds16(ag[r] + (K0), &Al[B][w * 16 + r * 8][0]);        \
    gload_lds16(bg[r] + (K0), &Bl[B][w * 16 + r * 8][0]);        \
  }

#define COMPUTE(B)                                                         \
  _Pragma("unroll")                                                        \
  for (int kk = 0; kk < 2; kk++) {                                         \
    int lc = kk * 4 + (lane >> 4);                                         \
    short8 af[4], bf[2];                                                   \
    _Pragma("unroll")                                                      \
    for (int m = 0; m < 4; m++) {                                          \
      int row = wr * 64 + m * 16 + (lane & 15);                            \
      af[m] = *(const short8*)&Al[B][row][(lc ^ (row & 7)) * 8];           \
    }                                                                      \
    _Pragma("unroll")                                                      \
    for (int n = 0; n < 2; n++) {                                          \
      int row = wc * 32 + n * 16 + (lane & 15);                            \
      bf[n] = *(const short8*)&Bl[B][row][(lc ^ (row & 7)) * 8];           \
    }                                                                      \
    _Pragma("unroll")                                                      \
    for (int m = 0; m < 4; m++)                                            \
      _Pragma("unroll")                                                    \
      for (int n = 0; n < 2; n++)                                          \
        acc[m][n] = __builtin_amdgcn_mfma_f32_16x16x32_bf16(af[m], bf[n],  \
                                                            acc[m][n], 0, 0, 0); \
  }

#define VWAIT4 asm volatile("s_waitcnt vmcnt(4)" ::: "memory")
#define VWAIT0 asm volatile("s_waitcnt vmcnt(0)" ::: "memory")
#define BARR  __builtin_amdgcn_s_barrier()
#define PIN   __builtin_amdgcn_sched_barrier(0)

  constexpr int NIT = AK / 64;   // 16 (pass2) / 8 (pass3) -- even, >= 4
  STAGE(0, 0)                    // 4 loads in flight (buf0)
  #pragma unroll 1
  for (int it = 0; it < NIT - 2; it += 2) {
    STAGE(1, (it + 1) * 64)      // +4 -> 8 in flight
    VWAIT4; BARR; PIN;           // buf0 done everywhere; buf1 loads still flying
    COMPUTE(0)
    BARR; PIN;                   // all waves done reading buf0 -> safe to overwrite
    STAGE(0, (it + 2) * 64)
    VWAIT4; BARR; PIN;           // buf1 done; buf0-next still flying
    COMPUTE(1)
    BARR; PIN;
  }
  // peeled tail: it = NIT-2
  STAGE(1, (NIT - 1) * 64)
  VWAIT4; BARR; PIN;
  COMPUTE(0)
  BARR; PIN;
  VWAIT0; BARR; PIN;             // drain buf1's loads
  COMPUTE(1)

#undef STAGE
#undef COMPUTE
#undef VWAIT4
#undef VWAIT0
#undef BARR
#undef PIN

  int cbase = n0 + wc * 32 + (lane & 15);
  #pragma unroll
  for (int m = 0; m < 4; m++) {
    int rbase = w >> 2 ? 64 + m * 16 + ((lane >> 4) << 2) : m * 16 + ((lane >> 4) << 2);
    rbase = wr * 64 + m * 16 + ((lane >> 4) << 2);   // C/D: col=lane&15, row=(lane>>4)*4+q
    #pragma unroll
    for (int q = 0; q < 4; q++) {
      int row = rbase + q;
      if (m0 + row >= cnt) continue;
      if (PASS == 2) {
        float aff = al[row];
        size_t base = (size_t)(pbe + m0 + row) * FEXP;   // contiguous list-order row
        #pragma unroll
        for (int n = 0; n < 2; n++) {
          float v = acc[m][n][q];
          float s = aff * v / (1.f + expf(-v));   // aff * silu(v)
          scores_out[base + cbase + n * 16] = f2bf(s);
        }
      } else {
        int tk = tl[row];
        size_t base = (size_t)(tk >> 3) * DMODEL;
        #pragma unroll
        for (int n = 0; n < 2; n++)
          atomicAdd(&out[base + cbase + n * 16], acc[m][n][q]);
      }
    }
  }
}

extern "C" void kernel_launch(void* const* d_in, const int* in_sizes, int n_in,
                              void* d_out, int out_size, void* d_ws, size_t ws_size,
                              hipStream_t stream) {
  (void)in_sizes; (void)n_in; (void)out_size; (void)ws_size;
  const float* token_stream    = (const float*)d_in[0];
  const float* selection_input = (const float*)d_in[1];
  const float* keys_w          = (const float*)d_in[2];
  const float* values_w        = (const float*)d_in[3];
  const float* expert_sel      = (const float*)d_in[4];
  const float* bias_ffn        = (const float*)d_in[5];

  float* out     = (float*)d_out;                       // [8192][1024] f32
  float* out_sel = out + (size_t)TOK_N * DMODEL;        // [8192][6] as float

  char* ws = (char*)d_ws;
  u16*      Xbf      = (u16*)(ws + 0);                  // 16 MB
  u16*      keysT    = (u16*)(ws + 16777216);           // 16 MB  [e][512][1024]
  u16*      valuesT  = (u16*)(ws + 33554432);           // 16 MB  [e][1024][512]
  u16*      scoresbf = (u16*)(ws + 50331648);           // 48 MB  [49152 list-order][512]
  int*      counts   = (int*)(ws + 100663296);          // 1 KB (padded, e -> counts[e*16])
  int*      tokk     = (int*)(ws + 100664320);          // 512 KB
  float*    affl     = (float*)(ws + 101188608);        // 512 KB
  unsigned* sel_pack = (unsigned*)(ws + 101712896);     // 32 KB
  float*    aff6     = (float*)(ws + 101745664);        // 192 KB
  int*      tiles    = (int*)(ws + 101942272);          // 4 KB
  int*      ntiles   = (int*)(ws + 101946368);          // 4 B
  int*      pbase    = (int*)(ws + 101946432);          // 64 B

  hipMemsetAsync(out, 0, (size_t)TOK_N * DMODEL * sizeof(float), stream);
  hipMemsetAsync(counts, 0, 1024, stream);

  // fused prologue: routing + cast + both transposes run CONCURRENTLY (one dispatch)
  prep_k<<<28672, 256, 0, stream>>>(token_stream, selection_input, keys_w, values_w,
                                    expert_sel, bias_ffn, Xbf, keysT, valuesT,
                                    out_sel, sel_pack, aff6);
  scatter_k<<<TOK_N / 256, 256, 0, stream>>>(sel_pack, aff6, counts, tokk, affl);
  tilelist_k<<<1, 64, 0, stream>>>(counts, tiles, ntiles, pbase);

  // scores = aff * silu(X @ K[e]):  M<=49152, N=512, K=1024
  moe_gemm_k<1024, 2, 4><<<MAXTILES * 4, 512, 0, stream>>>(Xbf, keysT, counts, tokk, affl,
                                                           tiles, ntiles, pbase,
                                                           scoresbf, nullptr);
  // out += scores @ V[e]:          M<=49152, N=1024, K=512
  moe_gemm_k<512, 3, 8><<<MAXTILES * 8, 512, 0, stream>>>(scoresbf, valuesT, counts, tokk, affl,
                                                          tiles, ntiles, pbase,
                                                          nullptr, out);
}